// Round 1
// baseline (87.402 us; speedup 1.0000x reference)
//
#include <hip/hip_runtime.h>
#include <hip/hip_bf16.h>

#define HD_D   2048
#define NW     32      // 2048 bits = 32 x uint64
#define NQ     16      // levels
#define NF     40      // features
#define NT     128     // time steps

// One block per batch element. 256 threads.
// Phase 1: pack level_hvs (16x2048 i32 of 0/1) and id_hvs (40x2048) into
//          uint64 words in LDS.
// Phase 2: quantize x[b] -> level indices in LDS.
// Phase 3: for each (f, w): seq[f][w] = XOR over t of roll(lvl[idx] ^ id[f], t) word w.
// Phase 4: for each d: cnt = sum_f bit(seq[f], d); out = cnt > 20 ? 1 : -1.
__global__ __launch_bounds__(256)
void Encoder_61753039782402_kernel(const float* __restrict__ x,
                                   const int* __restrict__ level_hvs,
                                   const int* __restrict__ id_hvs,
                                   float* __restrict__ out)
{
    __shared__ unsigned long long lvl[NQ][NW];   // 4 KiB
    __shared__ unsigned long long idh[NF][NW];   // 10 KiB
    __shared__ unsigned long long seq[NF][NW];   // 10 KiB
    __shared__ unsigned char     qidx[NT][NF];   // 5 KiB

    const int b   = blockIdx.x;
    const int tid = threadIdx.x;

    // ---- Phase 1: bit-pack level + id hypervectors into LDS ----
    for (int i = tid; i < (NQ + NF) * NW; i += 256) {
        const int r = i / NW;
        const int w = i % NW;
        const int* src = (r < NQ) ? (level_hvs + r * HD_D + w * 64)
                                  : (id_hvs + (r - NQ) * HD_D + w * 64);
        unsigned long long v = 0ULL;
        #pragma unroll
        for (int k = 0; k < 64; ++k)
            v |= ((unsigned long long)(src[k] & 1)) << k;
        if (r < NQ) lvl[r][w] = v;
        else        idh[r - NQ][w] = v;
    }

    // ---- Phase 2: quantize x for this batch ----
    for (int i = tid; i < NT * NF; i += 256) {
        const int t = i / NF;
        const int f = i % NF;
        const float xv = x[(b * NT + t) * NF + f];
        // trunc-toward-zero like astype(int32); value in [-1, 14]; wrap mod 16
        int v = (int)(xv * 16.0f - 1.0f);
        qidx[t][f] = (unsigned char)((v + 16) & 15);
    }
    __syncthreads();

    // ---- Phase 3: per (f, w) XOR-accumulate rolled rows over time ----
    for (int i = tid; i < NF * NW; i += 256) {
        const int f = i / NW;
        const int w = i % NW;
        unsigned long long acc = 0ULL;
        for (int t = 0; t < NT; ++t) {
            const int tw = t >> 6;       // word shift
            const int tb = t & 63;       // bit shift
            const int j  = (w - tw) & (NW - 1);
            const int j2 = (w - tw - 1) & (NW - 1);
            const int li = qidx[t][f];
            const unsigned long long r1 = lvl[li][j]  ^ idh[f][j];
            const unsigned long long r2 = lvl[li][j2] ^ idh[f][j2];
            acc ^= tb ? ((r1 << tb) | (r2 >> (64 - tb))) : r1;
        }
        seq[f][w] = acc;
    }
    __syncthreads();

    // ---- Phase 4: per bit-position count over features, threshold ----
    for (int d = tid; d < HD_D; d += 256) {
        const int w   = d >> 6;
        const int bit = d & 63;
        int cnt = 0;
        #pragma unroll
        for (int f = 0; f < NF; ++f)
            cnt += (int)((seq[f][w] >> bit) & 1ULL);
        // hv = 2*cnt - 40; out = hv > 0 ? 1 : -1  <=>  cnt > 20
        out[b * HD_D + d] = (cnt > 20) ? 1.0f : -1.0f;
    }
}

extern "C" void kernel_launch(void* const* d_in, const int* in_sizes, int n_in,
                              void* d_out, int out_size, void* d_ws, size_t ws_size,
                              hipStream_t stream)
{
    const float* x         = (const float*)d_in[0];  // [8,128,40] f32
    const int*   level_hvs = (const int*)d_in[1];    // [16,2048] i32
    const int*   id_hvs    = (const int*)d_in[2];    // [40,2048] i32
    float*       out       = (float*)d_out;          // [8,2048] f32

    Encoder_61753039782402_kernel<<<8, 256, 0, stream>>>(x, level_hvs, id_hvs, out);
}

// Round 2
// 32.856 us; speedup vs baseline: 2.6602x; 2.6602x over previous
//
#include <hip/hip_runtime.h>
#include <hip/hip_bf16.h>

#define HD_D   2048
#define NW     32      // 2048 bits = 32 x uint64
#define NQ     16      // levels
#define NF     40      // features
#define NB     8       // batch
#define NT     128     // time steps

typedef unsigned long long u64;

// Workspace layout (bytes):
//   [0,                14336)  packed HVs: u64[56][32]  (rows 0..15 = level, 16..55 = id)
//   [14336,            55296)  qidx: u8[8][128][40]
//   [55296,           137216)  seq: u64[8][40][32]
#define WS_PACK_OFF  0
#define WS_QIDX_OFF  14336
#define WS_SEQ_OFF   55296

// ---------------- K1: pack HVs (ballot) + quantize x ----------------
// blocks 0..6  : 28 waves pack 1792 u64 words (64 words/wave)
// blocks 7..31 : quantize 8*128*40 = 40960 values (grid-stride)
__global__ __launch_bounds__(256)
void k1_pack_quant(const float* __restrict__ x,
                   const int* __restrict__ level_hvs,
                   const int* __restrict__ id_hvs,
                   void* __restrict__ ws)
{
    const int tid = threadIdx.x;
    if (blockIdx.x < 7) {
        u64* pack = (u64*)((char*)ws + WS_PACK_OFF);
        const int wave = blockIdx.x * 4 + (tid >> 6);  // 0..27
        const int lane = tid & 63;
        const int base = wave * 64;                    // first word of this wave
        for (int k = 0; k < 64; ++k) {
            const int wi  = base + k;                  // word index 0..1791
            const int row = wi >> 5;                   // 0..55
            const int col = wi & 31;
            const int* src = (row < NQ)
                ? (level_hvs + row * HD_D + col * 64)
                : (id_hvs + (row - NQ) * HD_D + col * 64);
            const u64 m = __ballot(src[lane] & 1);
            if (lane == 0) pack[wi] = m;
        }
    } else {
        unsigned char* q = (unsigned char*)ws + WS_QIDX_OFF;
        const int nthr = (gridDim.x - 7) * 256;
        for (int i = (blockIdx.x - 7) * 256 + tid; i < NB * NT * NF; i += nthr) {
            // x flat layout [b][t][f] == qidx layout
            int v = (int)(x[i] * 16.0f - 1.0f);        // trunc toward zero, in [-1,14]
            q[i] = (unsigned char)((v + 16) & 15);     // numpy wrap
        }
    }
}

// ---------------- K2: per-(b,f) XOR over time of rolled bound rows ----------------
// grid = B*F = 320 blocks, 128 threads. thread = (w = tid&31, th = tid>>5).
// th selects a 32-step t-quarter; tw = t>>6 is constant per quarter, so the
// word indices j, j2 and idh[j], idh[j2] hoist out of the inner loop.
__global__ __launch_bounds__(128)
void k2_seq(const void* __restrict__ ws_in, void* __restrict__ ws_out)
{
    __shared__ u64 lvl[NQ][NW];      // 4 KiB
    __shared__ u64 idh[NW];          // 256 B
    __shared__ unsigned char qf[NT]; // 128 B
    __shared__ u64 partial[128];     // 1 KiB

    const u64* pack = (const u64*)((const char*)ws_in + WS_PACK_OFF);
    const unsigned char* q = (const unsigned char*)ws_in + WS_QIDX_OFF;
    u64* seq = (u64*)((char*)ws_out + WS_SEQ_OFF);

    const int b = blockIdx.x / NF;
    const int f = blockIdx.x % NF;
    const int tid = threadIdx.x;

    // load packed level HVs (512 words), id row f (32 words), q indices (128 B)
    for (int i = tid; i < NQ * NW; i += 128)
        lvl[i >> 5][i & 31] = pack[i];
    if (tid < NW)
        idh[tid] = pack[NQ * NW + f * NW + tid];
    if (tid < NT)
        qf[tid] = q[b * (NT * NF) + tid * NF + f];
    __syncthreads();

    const int w  = tid & 31;
    const int th = tid >> 5;          // 0..3 -> t in [th*32, th*32+32)
    const int t0 = th * 32;
    const int tw = t0 >> 6;           // constant over the quarter
    const int j  = (w - tw) & (NW - 1);
    const int j2 = (w - tw - 1) & (NW - 1);
    const u64 ij  = idh[j];
    const u64 ij2 = idh[j2];

    u64 acc = 0ULL;
    for (int k = 0; k < 32; ++k) {
        const int t  = t0 + k;
        const int tb = t & 63;
        const int li = qf[t];
        const u64 r1 = lvl[li][j]  ^ ij;
        const u64 r2 = lvl[li][j2] ^ ij2;
        acc ^= tb ? ((r1 << tb) | (r2 >> (64 - tb))) : r1;
    }
    partial[tid] = acc;
    __syncthreads();
    if (tid < NW) {
        const u64 s = partial[tid] ^ partial[tid + 32] ^ partial[tid + 64] ^ partial[tid + 96];
        seq[(b * NF + f) * NW + tid] = s;
    }
}

// ---------------- K3: bit-sliced bundle + threshold ----------------
// 8 blocks (one per batch) x 64 threads.
__global__ __launch_bounds__(64)
void k3_bundle(const void* __restrict__ ws, float* __restrict__ out)
{
    __shared__ u64 sq[NF][NW];   // 10 KiB
    __shared__ u64 mask[NW];

    const u64* seq = (const u64*)((const char*)ws + WS_SEQ_OFF);
    const int b = blockIdx.x;
    const int tid = threadIdx.x;

    for (int i = tid; i < NF * NW; i += 64)
        sq[i >> 5][i & 31] = seq[b * NF * NW + i];
    __syncthreads();

    if (tid < NW) {
        const int w = tid;
        // bit-sliced add of 40 one-bit values per bit position (max 40 < 64)
        u64 c0 = 0, c1 = 0, c2 = 0, c3 = 0, c4 = 0, c5 = 0;
        #pragma unroll
        for (int f = 0; f < NF; ++f) {
            u64 c = sq[f][w];
            u64 t;
            t = c0 & c; c0 ^= c; c = t;
            t = c1 & c; c1 ^= c; c = t;
            t = c2 & c; c2 ^= c; c = t;
            t = c3 & c; c3 ^= c; c = t;
            t = c4 & c; c4 ^= c; c = t;
            c5 ^= c;
        }
        // cnt > 20 (20 = 0b010100):
        mask[w] = c5 | (c4 & (c3 | (c2 & (c1 | c0))));
    }
    __syncthreads();

    for (int d = tid; d < HD_D; d += 64)
        out[b * HD_D + d] = ((mask[d >> 6] >> (d & 63)) & 1ULL) ? 1.0f : -1.0f;
}

extern "C" void kernel_launch(void* const* d_in, const int* in_sizes, int n_in,
                              void* d_out, int out_size, void* d_ws, size_t ws_size,
                              hipStream_t stream)
{
    const float* x         = (const float*)d_in[0];  // [8,128,40] f32
    const int*   level_hvs = (const int*)d_in[1];    // [16,2048] i32
    const int*   id_hvs    = (const int*)d_in[2];    // [40,2048] i32
    float*       out       = (float*)d_out;          // [8,2048] f32

    k1_pack_quant<<<32, 256, 0, stream>>>(x, level_hvs, id_hvs, d_ws);
    k2_seq<<<NB * NF, 128, 0, stream>>>(d_ws, d_ws);
    k3_bundle<<<NB, 64, 0, stream>>>(d_ws, out);
}

// Round 3
// 11.030 us; speedup vs baseline: 7.9243x; 2.9788x over previous
//
#include <hip/hip_runtime.h>
#include <hip/hip_bf16.h>

#define HD_D   2048
#define NW     32      // 2048 bits = 32 x uint64
#define NQ     16      // levels
#define NF     40      // features
#define NB     8       // batch
#define NT     128     // time steps

typedef unsigned long long u64;

// Fully fused: grid = NB*NW = 256 blocks (one per CU), 256 threads.
// Block (b, w) computes output bits d in [w*64, w*64+64) for batch b.
// Since T=128, tw = t>>6 is only 0 or 1, so word w of the rolled row only
// ever touches source words {w-2, w-1, w}: each block packs just 56 rows
// x 3 words itself (per-thread int4 loads — no cross-block handoff).
__global__ __launch_bounds__(256)
void enc_fused(const float* __restrict__ x,
               const int* __restrict__ level_hvs,
               const int* __restrict__ id_hvs,
               float* __restrict__ out)
{
    __shared__ u64 lvlw[NQ][3];            // level rows, slots = words (w-2, w-1, w)
    __shared__ u64 idw[NF][3];             // id rows, same 3 slots
    __shared__ unsigned char qidx[NT * NF];// quantized x[b], layout [t][f]
    __shared__ u64 partial[160];           // (f, quarter) partial XORs
    __shared__ u64 seqw[NF];               // per-f seq word at this w

    const int b   = blockIdx.x >> 5;
    const int w   = blockIdx.x & 31;
    const int tid = threadIdx.x;

    // ---- quantize x[b]: 5120 floats as 1280 float4 (coalesced) ----
    const float4* xb = (const float4*)(x + b * NT * NF);
    #pragma unroll
    for (int r = 0; r < 5; ++r) {
        const int i4 = tid + r * 256;
        const float4 v = xb[i4];
        unsigned int p;
        p  = ((unsigned)(((int)(v.x * 16.0f - 1.0f) + 16) & 15));
        p |= ((unsigned)(((int)(v.y * 16.0f - 1.0f) + 16) & 15)) << 8;
        p |= ((unsigned)(((int)(v.z * 16.0f - 1.0f) + 16) & 15)) << 16;
        p |= ((unsigned)(((int)(v.w * 16.0f - 1.0f) + 16) & 15)) << 24;
        *(unsigned int*)(qidx + i4 * 4) = p;
    }

    // ---- pack the 56x3 needed HV words; one thread per word ----
    if (tid < (NQ + NF) * 3) {
        const int row  = tid / 3;               // 0..55
        const int slot = tid % 3;                // word col (w-2+slot) & 31
        const int col  = (w + slot - 2) & (NW - 1);
        const int* src = (row < NQ)
            ? (level_hvs + row * HD_D + col * 64)
            : (id_hvs + (row - NQ) * HD_D + col * 64);
        const int4* s4 = (const int4*)src;
        u64 v = 0;
        #pragma unroll
        for (int c = 0; c < 16; ++c) {
            const int4 e = s4[c];
            v |= ((u64)(e.x & 1)) << (c * 4 + 0);
            v |= ((u64)(e.y & 1)) << (c * 4 + 1);
            v |= ((u64)(e.z & 1)) << (c * 4 + 2);
            v |= ((u64)(e.w & 1)) << (c * 4 + 3);
        }
        if (row < NQ) lvlw[row][slot] = v;
        else          idw[row - NQ][slot] = v;
    }
    __syncthreads();

    // ---- seq: tid = f*4 + q, q = 32-step time quarter ----
    if (tid < NF * 4) {
        const int f  = tid >> 2;
        const int q  = tid & 3;
        const int t0 = q * 32;
        const int tw = q >> 1;           // t>>6, constant over the quarter
        const int i1 = 2 - tw;           // slot of word j  = (w - tw) & 31
        const int i2 = 1 - tw;           // slot of word j2 = (w - tw - 1) & 31
        const u64 ih1 = idw[f][i1];
        const u64 ih2 = idw[f][i2];
        u64 acc = 0ULL;
        for (int k = 0; k < 32; ++k) {
            const int t  = t0 + k;
            const int tb = ((q & 1) << 5) | k;     // t & 63
            const int li = qidx[t * NF + f];
            const u64 r1 = lvlw[li][i1] ^ ih1;
            const u64 r2 = lvlw[li][i2] ^ ih2;
            const u64 lo = tb ? (r2 >> ((64 - tb) & 63)) : 0ULL;
            acc ^= (r1 << tb) | lo;
        }
        partial[tid] = acc;
    }
    __syncthreads();

    if (tid < NF)
        seqw[tid] = partial[tid * 4] ^ partial[tid * 4 + 1]
                  ^ partial[tid * 4 + 2] ^ partial[tid * 4 + 3];
    __syncthreads();

    // ---- bundle over features + hard quantize; 64 contiguous floats ----
    if (tid < 64) {
        int cnt = 0;
        #pragma unroll
        for (int f = 0; f < NF; ++f)
            cnt += (int)((seqw[f] >> tid) & 1ULL);   // broadcast LDS reads
        out[b * HD_D + w * 64 + tid] = (cnt > 20) ? 1.0f : -1.0f;
    }
}

extern "C" void kernel_launch(void* const* d_in, const int* in_sizes, int n_in,
                              void* d_out, int out_size, void* d_ws, size_t ws_size,
                              hipStream_t stream)
{
    const float* x         = (const float*)d_in[0];  // [8,128,40] f32
    const int*   level_hvs = (const int*)d_in[1];    // [16,2048] i32
    const int*   id_hvs    = (const int*)d_in[2];    // [40,2048] i32
    float*       out       = (float*)d_out;          // [8,2048] f32

    enc_fused<<<NB * NW, 256, 0, stream>>>(x, level_hvs, id_hvs, out);
}